// Round 1
// baseline (383.330 us; speedup 1.0000x reference)
//
#include <hip/hip_runtime.h>

#define N 4096
#define C 64
#define B 4

typedef __attribute__((ext_vector_type(8))) short short8;
typedef __attribute__((ext_vector_type(4))) float f32x4;

#define MFMA16(a, b, c) __builtin_amdgcn_mfma_f32_16x16x32_bf16(a, b, c, 0, 0, 0)

__device__ __forceinline__ short f2bf(float f) {
    unsigned u = __builtin_bit_cast(unsigned, f);
    u += 0x7fffu + ((u >> 16) & 1u);   // round-to-nearest-even; inputs are finite
    return (short)(u >> 16);
}

// -------- Phase A: per-node projection, e2, bf16 conversions --------
// grid: N/4 blocks x 256 threads. wave w handles node n = blockIdx*4 + w.
// lane = output channel o. h[b,n,o] = sum_c x[b,n,c]*W[n,c,o] + pb[n,o]
__global__ __launch_bounds__(256) void proj_kernel(
    const float* __restrict__ x,       // B,N,C
    const float* __restrict__ proj_w,  // N,C,C
    const float* __restrict__ proj_b,  // N,C
    const float* __restrict__ a_w,     // N,2C
    short* __restrict__ h_bf,          // B,N,C  (bf16 bits)
    short* __restrict__ hT_bf,         // B,C,N  (bf16 bits)
    short* __restrict__ a_srcb,        // N,C    (bf16 bits)
    float* __restrict__ e2)            // B,N
{
    const int wave = threadIdx.x >> 6;
    const int lane = threadIdx.x & 63;
    const int n = blockIdx.x * 4 + wave;
    const int o = lane;

    const float* Wn = proj_w + (size_t)n * C * C;

    // lane l holds x[b][n][l]; broadcast via shuffle in the c-loop
    float xv[B];
#pragma unroll
    for (int b = 0; b < B; b++) xv[b] = x[((size_t)b * N + n) * C + lane];

    float acc[B];
#pragma unroll
    for (int b = 0; b < B; b++) acc[b] = proj_b[(size_t)n * C + o];

    for (int c = 0; c < C; c++) {
        float w = Wn[c * C + o];  // 64 lanes -> 256B coalesced
#pragma unroll
        for (int b = 0; b < B; b++) {
            float xc = __shfl(xv[b], c, 64);
            acc[b] = fmaf(xc, w, acc[b]);
        }
    }

    float asrc = a_w[(size_t)n * (2 * C) + o];
    float adst = a_w[(size_t)n * (2 * C) + C + o];
    a_srcb[(size_t)n * C + o] = f2bf(asrc);

#pragma unroll
    for (int b = 0; b < B; b++) {
        short hb = f2bf(acc[b]);
        h_bf[((size_t)b * N + n) * C + o] = hb;
        hT_bf[(size_t)b * C * N + (size_t)o * N + n] = hb;
        float prod = acc[b] * adst;  // e2 in fp32 from fp32 h
#pragma unroll
        for (int off = 32; off; off >>= 1) prod += __shfl_xor(prod, off, 64);
        if (lane == 0) e2[b * N + n] = prod;
    }
}

// -------- Phase B: fused flash-style attention --------
// grid: N/16 blocks x 256 threads. wave = batch b; each wave owns 16 i-rows.
// j-loop in tiles of 64. dist tile staged in LDS once per block (shared by 4 batches).
__global__ __launch_bounds__(256) void attn_kernel(
    const float* __restrict__ dist,    // N,N
    const short* __restrict__ h_bf,    // B,N,C
    const short* __restrict__ hT_bf,   // B,C,N
    const short* __restrict__ a_srcb,  // N,C
    const float* __restrict__ e2,      // B,N
    float* __restrict__ out)           // B,N,C
{
    __shared__ float lds_dist[16 * 68];      // stride 68: conflict-free reads, 16B-aligned stores
    __shared__ short lds_p[4][16 * 72];      // per-wave P tile, stride 72 (16B-aligned b128 reads)

    const int tid = threadIdx.x;
    const int wave = tid >> 6;
    const int lane = tid & 63;
    const int cl = lane & 15;    // col-within-16 / A-operand row
    const int rg = lane >> 4;    // quad group
    const int b = wave;
    const int i0 = blockIdx.x * 16;

    // Persistent A-frags: H_i rows (m = cl), k = ks*32 + rg*8 + jj
    const short* hrow = h_bf + ((size_t)b * N + i0 + cl) * C;
    short8 af0 = *(const short8*)(hrow + rg * 8);
    short8 af1 = *(const short8*)(hrow + 32 + rg * 8);

    f32x4 yacc[4];
#pragma unroll
    for (int t = 0; t < 4; t++) { f32x4 z = {0.f, 0.f, 0.f, 0.f}; yacc[t] = z; }
    float mrow[4] = {-1e30f, -1e30f, -1e30f, -1e30f};  // per local row rg*4+r
    float lrow[4] = {0.f, 0.f, 0.f, 0.f};

    for (int j0 = 0; j0 < N; j0 += 64) {
        __syncthreads();  // protect lds_dist from previous iteration's readers
        {
            int r = tid >> 4;            // 0..15
            int cc = (tid & 15) * 4;     // 0..60
            const float4* src = (const float4*)(dist + (size_t)(i0 + r) * N + j0 + cc);
            *(float4*)(&lds_dist[r * 68 + cc]) = *src;
        }
        __syncthreads();

        // ---- S = H_i @ a_src^T  (gemm-bt) ----
        f32x4 sacc[4];
#pragma unroll
        for (int t = 0; t < 4; t++) {
            f32x4 z = {0.f, 0.f, 0.f, 0.f};
            const short* arow = a_srcb + (size_t)(j0 + t * 16 + cl) * C + rg * 8;
            short8 b0 = *(const short8*)(arow);
            short8 b1 = *(const short8*)(arow + 32);
            z = MFMA16(af0, b0, z);
            z = MFMA16(af1, b1, z);
            sacc[t] = z;
        }

        float e2v[4];
#pragma unroll
        for (int t = 0; t < 4; t++) e2v[t] = e2[b * N + j0 + t * 16 + cl];

        // ---- epilogue: +e2, leaky-relu, adjacency mask ----
        float p[4][4];                       // [t][reg]
        float mcur[4] = {-1e30f, -1e30f, -1e30f, -1e30f};
#pragma unroll
        for (int t = 0; t < 4; t++) {
#pragma unroll
            for (int r = 0; r < 4; r++) {
                float sv = sacc[t][r] + e2v[t];
                sv = (sv >= 0.f) ? sv : 0.01f * sv;
                int row = rg * 4 + r;
                float d = lds_dist[row * 68 + t * 16 + cl];
                bool adj = (d > 0.f && d < 0.5f) || (i0 + row == j0 + t * 16 + cl);
                sv = adj ? sv : -1e15f;
                p[t][r] = sv;
                mcur[r] = fmaxf(mcur[r], sv);
            }
        }

        // ---- online softmax (state replicated across the 16 lanes of each quad row-group) ----
        float alpha[4];
#pragma unroll
        for (int r = 0; r < 4; r++) {
            float mx = mcur[r];
#pragma unroll
            for (int off = 8; off; off >>= 1) mx = fmaxf(mx, __shfl_xor(mx, off, 64));
            float mnew = fmaxf(mrow[r], mx);
            alpha[r] = __expf(mrow[r] - mnew);
            mrow[r] = mnew;
            float ps = 0.f;
#pragma unroll
            for (int t = 0; t < 4; t++) {
                float pv = __expf(p[t][r] - mnew);
                p[t][r] = pv;
                ps += pv;
            }
#pragma unroll
            for (int off = 8; off; off >>= 1) ps += __shfl_xor(ps, off, 64);
            lrow[r] = lrow[r] * alpha[r] + ps;
        }

#pragma unroll
        for (int t = 0; t < 4; t++)
#pragma unroll
            for (int r = 0; r < 4; r++) yacc[t][r] *= alpha[r];

        // ---- P: C-layout -> A-layout via per-wave LDS tile ----
        short* lp = lds_p[wave];
#pragma unroll
        for (int t = 0; t < 4; t++)
#pragma unroll
            for (int r = 0; r < 4; r++)
                lp[(rg * 4 + r) * 72 + t * 16 + cl] = f2bf(p[t][r]);
        // same-wave LDS write->read: in-order / compiler-sequenced, no barrier needed
        short8 pa0 = *(const short8*)(lp + cl * 72 + rg * 8);
        short8 pa1 = *(const short8*)(lp + cl * 72 + 32 + rg * 8);

        // ---- Y += P @ H_j  (B-operand from hT: contiguous in j) ----
#pragma unroll
        for (int t = 0; t < 4; t++) {
            const short* hc = hT_bf + (size_t)b * C * N + (size_t)(t * 16 + cl) * N + j0 + rg * 8;
            short8 h0 = *(const short8*)(hc);
            short8 h1 = *(const short8*)(hc + 32);
            yacc[t] = MFMA16(pa0, h0, yacc[t]);
            yacc[t] = MFMA16(pa1, h1, yacc[t]);
        }
    }

    // ---- write y = acc / l ----
#pragma unroll
    for (int t = 0; t < 4; t++)
#pragma unroll
        for (int r = 0; r < 4; r++) {
            int row = i0 + rg * 4 + r;
            out[((size_t)b * N + row) * C + t * 16 + cl] = yacc[t][r] / lrow[r];
        }
}

extern "C" void kernel_launch(void* const* d_in, const int* in_sizes, int n_in,
                              void* d_out, int out_size, void* d_ws, size_t ws_size,
                              hipStream_t stream) {
    const float* x      = (const float*)d_in[0];
    const float* dist   = (const float*)d_in[1];
    const float* proj_w = (const float*)d_in[2];
    const float* proj_b = (const float*)d_in[3];
    const float* a_w    = (const float*)d_in[4];
    float* out = (float*)d_out;

    char* ws = (char*)d_ws;
    short* h_bf   = (short*)(ws);                               // B*N*C bf16 = 2 MB
    short* hT_bf  = (short*)(ws + (2u << 20));                  // B*C*N bf16 = 2 MB
    short* a_srcb = (short*)(ws + (4u << 20));                  // N*C bf16 = 512 KB
    float* e2     = (float*)(ws + (4u << 20) + (512u << 10));   // B*N f32 = 64 KB

    proj_kernel<<<N / 4, 256, 0, stream>>>(x, proj_w, proj_b, a_w, h_bf, hT_bf, a_srcb, e2);
    attn_kernel<<<N / 16, 256, 0, stream>>>(dist, h_bf, hT_bf, a_srcb, e2, out);
}

// Round 2
// 286.913 us; speedup vs baseline: 1.3360x; 1.3360x over previous
//
#include <hip/hip_runtime.h>

#define N 4096
#define C 64
#define B 4

typedef __attribute__((ext_vector_type(8))) short short8;
typedef __attribute__((ext_vector_type(4))) float f32x4;

#define MFMA16(a, b, c) __builtin_amdgcn_mfma_f32_16x16x32_bf16(a, b, c, 0, 0, 0)

__device__ __forceinline__ short f2bf(float f) {
    unsigned u = __builtin_bit_cast(unsigned, f);
    u += 0x7fffu + ((u >> 16) & 1u);   // RNE; inputs finite
    return (short)(u >> 16);
}

// -------- Phase A: per-node projection, e2, bf16 conversions --------
// One block (4 waves) per node. Lane loads float4 of a W row -> 1KB/wave
// vector loads; wave w covers k-rows [w*16, w*16+16); butterfly + LDS reduce.
__global__ __launch_bounds__(256) void proj_kernel(
    const float* __restrict__ x,       // B,N,C
    const float* __restrict__ proj_w,  // N,C,C
    const float* __restrict__ proj_b,  // N,C
    const float* __restrict__ a_w,     // N,2C
    short* __restrict__ h_bf,          // B,N,C
    short* __restrict__ hT_bf,         // B,C,N
    short* __restrict__ a_srcb,        // N,C
    float* __restrict__ e2)            // B,N
{
    __shared__ float lds_x[B][C];
    __shared__ float lds_acc[4][B][C];

    const int tid = threadIdx.x;
    const int wave = tid >> 6;
    const int lane = tid & 63;
    const int n = blockIdx.x;

    lds_x[wave][lane] = x[((size_t)wave * N + n) * C + lane];  // wave==b here
    __syncthreads();

    const int o4 = (lane & 15) * 4;  // output-channel group
    const int cl = lane >> 4;        // 0..3: k-subrow within iteration
    const float* Wn = proj_w + (size_t)n * C * C;

    float4 acc[B];
#pragma unroll
    for (int b = 0; b < B; b++) acc[b] = make_float4(0.f, 0.f, 0.f, 0.f);

#pragma unroll
    for (int i = 0; i < 4; i++) {
        int c = wave * 16 + i * 4 + cl;
        float4 wv = *(const float4*)(Wn + c * C + o4);  // wave reads 1KB contiguous
#pragma unroll
        for (int b = 0; b < B; b++) {
            float xc = lds_x[b][c];
            acc[b].x = fmaf(xc, wv.x, acc[b].x);
            acc[b].y = fmaf(xc, wv.y, acc[b].y);
            acc[b].z = fmaf(xc, wv.z, acc[b].z);
            acc[b].w = fmaf(xc, wv.w, acc[b].w);
        }
    }
    // reduce over cl (lanes ^16, ^32 hold other k-subrows, same o4)
#pragma unroll
    for (int b = 0; b < B; b++) {
#pragma unroll
        for (int off = 16; off < 64; off <<= 1) {
            acc[b].x += __shfl_xor(acc[b].x, off, 64);
            acc[b].y += __shfl_xor(acc[b].y, off, 64);
            acc[b].z += __shfl_xor(acc[b].z, off, 64);
            acc[b].w += __shfl_xor(acc[b].w, off, 64);
        }
        if (lane < 16) *(float4*)(&lds_acc[wave][b][o4]) = acc[b];
    }
    __syncthreads();

    // final: wave = b, lane = o
    {
        const int b = wave, o = lane;
        float hval = proj_b[(size_t)n * C + o] + lds_acc[0][b][o] + lds_acc[1][b][o] +
                     lds_acc[2][b][o] + lds_acc[3][b][o];
        float adst = a_w[(size_t)n * (2 * C) + C + o];
        short hb = f2bf(hval);
        h_bf[((size_t)b * N + n) * C + o] = hb;
        hT_bf[(size_t)b * C * N + (size_t)o * N + n] = hb;
        float prod = hval * adst;
#pragma unroll
        for (int off = 32; off; off >>= 1) prod += __shfl_xor(prod, off, 64);
        if (lane == 0) e2[b * N + n] = prod;
        if (tid < C) a_srcb[(size_t)n * C + tid] = f2bf(a_w[(size_t)n * (2 * C) + tid]);
    }
}

// -------- Phase B pass 1: flash attention over a j-stripe --------
// grid: (N/16, S). blockIdx.y = stripe. wave = batch, 16 i-rows/wave.
// mode==1: S==1, write normalized output directly (no combine).
__global__ __launch_bounds__(256) void attn_kernel(
    const float* __restrict__ dist,    // N,N
    const short* __restrict__ h_bf,    // B,N,C
    const short* __restrict__ hT_bf,   // B,C,N
    const short* __restrict__ a_srcb,  // N,C
    const float* __restrict__ e2,      // B,N
    float* __restrict__ part_y,        // [S,B,N,C] or out [B,N,C] if mode
    float* __restrict__ part_m,        // [S,B,N]
    float* __restrict__ part_l,        // [S,B,N]
    int JS, int mode)
{
    __shared__ float lds_dist[16 * 68];
    __shared__ short lds_p[4][16 * 72];

    const int tid = threadIdx.x;
    const int wave = tid >> 6;
    const int lane = tid & 63;
    const int cl = lane & 15;
    const int rg = lane >> 4;
    const int b = wave;
    const int i0 = blockIdx.x * 16;
    const int sidx = blockIdx.y;
    const int jbeg = sidx * JS;

    const short* hrow = h_bf + ((size_t)b * N + i0 + cl) * C;
    short8 af0 = *(const short8*)(hrow + rg * 8);
    short8 af1 = *(const short8*)(hrow + 32 + rg * 8);

    f32x4 yacc[4];
#pragma unroll
    for (int t = 0; t < 4; t++) { f32x4 z = {0.f, 0.f, 0.f, 0.f}; yacc[t] = z; }
    float mrow[4] = {-1e30f, -1e30f, -1e30f, -1e30f};
    float lrow[4] = {0.f, 0.f, 0.f, 0.f};

    for (int j0 = jbeg; j0 < jbeg + JS; j0 += 64) {
        __syncthreads();
        {
            int r = tid >> 4;
            int cc = (tid & 15) * 4;
            *(float4*)(&lds_dist[r * 68 + cc]) =
                *(const float4*)(dist + (size_t)(i0 + r) * N + j0 + cc);
        }
        __syncthreads();

        // S = H_i @ a_src^T
        f32x4 sacc[4];
#pragma unroll
        for (int t = 0; t < 4; t++) {
            f32x4 z = {0.f, 0.f, 0.f, 0.f};
            const short* arow = a_srcb + (size_t)(j0 + t * 16 + cl) * C + rg * 8;
            short8 b0 = *(const short8*)(arow);
            short8 b1 = *(const short8*)(arow + 32);
            z = MFMA16(af0, b0, z);
            z = MFMA16(af1, b1, z);
            sacc[t] = z;
        }

        float e2v[4];
#pragma unroll
        for (int t = 0; t < 4; t++) e2v[t] = e2[b * N + j0 + t * 16 + cl];

        float p[4][4];
        float mcur[4] = {-1e30f, -1e30f, -1e30f, -1e30f};
#pragma unroll
        for (int t = 0; t < 4; t++) {
#pragma unroll
            for (int r = 0; r < 4; r++) {
                float sv = sacc[t][r] + e2v[t];
                sv = (sv >= 0.f) ? sv : 0.01f * sv;
                int row = rg * 4 + r;
                float d = lds_dist[row * 68 + t * 16 + cl];
                bool adj = (d > 0.f && d < 0.5f) || (i0 + row == j0 + t * 16 + cl);
                sv = adj ? sv : -1e15f;
                p[t][r] = sv;
                mcur[r] = fmaxf(mcur[r], sv);
            }
        }

        float alpha[4];
#pragma unroll
        for (int r = 0; r < 4; r++) {
            float mx = mcur[r];
#pragma unroll
            for (int off = 8; off; off >>= 1) mx = fmaxf(mx, __shfl_xor(mx, off, 64));
            float mnew = fmaxf(mrow[r], mx);
            alpha[r] = __expf(mrow[r] - mnew);
            mrow[r] = mnew;
            float ps = 0.f;
#pragma unroll
            for (int t = 0; t < 4; t++) {
                float pv = __expf(p[t][r] - mnew);
                p[t][r] = pv;
                ps += pv;
            }
#pragma unroll
            for (int off = 8; off; off >>= 1) ps += __shfl_xor(ps, off, 64);
            lrow[r] = lrow[r] * alpha[r] + ps;
        }

#pragma unroll
        for (int t = 0; t < 4; t++)
#pragma unroll
            for (int r = 0; r < 4; r++) yacc[t][r] *= alpha[r];

        short* lp = lds_p[wave];
#pragma unroll
        for (int t = 0; t < 4; t++)
#pragma unroll
            for (int r = 0; r < 4; r++)
                lp[(rg * 4 + r) * 72 + t * 16 + cl] = f2bf(p[t][r]);
        short8 pa0 = *(const short8*)(lp + cl * 72 + rg * 8);
        short8 pa1 = *(const short8*)(lp + cl * 72 + 32 + rg * 8);

#pragma unroll
        for (int t = 0; t < 4; t++) {
            const short* hc = hT_bf + (size_t)b * C * N + (size_t)(t * 16 + cl) * N + j0 + rg * 8;
            short8 h0 = *(const short8*)(hc);
            short8 h1 = *(const short8*)(hc + 32);
            yacc[t] = MFMA16(pa0, h0, yacc[t]);
            yacc[t] = MFMA16(pa1, h1, yacc[t]);
        }
    }

    if (mode) {
#pragma unroll
        for (int t = 0; t < 4; t++)
#pragma unroll
            for (int r = 0; r < 4; r++)
                part_y[((size_t)b * N + i0 + rg * 4 + r) * C + t * 16 + cl] =
                    yacc[t][r] / lrow[r];
    } else {
        size_t sb = (size_t)(sidx * B + b) * N;
#pragma unroll
        for (int t = 0; t < 4; t++)
#pragma unroll
            for (int r = 0; r < 4; r++)
                part_y[(sb + i0 + rg * 4 + r) * C + t * 16 + cl] = yacc[t][r];
        if (cl == 0) {
#pragma unroll
            for (int r = 0; r < 4; r++) {
                part_m[sb + i0 + rg * 4 + r] = mrow[r];
                part_l[sb + i0 + rg * 4 + r] = lrow[r];
            }
        }
    }
}

// -------- Phase B pass 2: merge stripes --------
__global__ __launch_bounds__(256) void combine_kernel(
    const float* __restrict__ part_y, const float* __restrict__ part_m,
    const float* __restrict__ part_l, float* __restrict__ out, int S)
{
    int g = blockIdx.x * 256 + threadIdx.x;  // over B*N*C
    int c = g & 63;
    int row = (g >> 6) & (N - 1);
    int b = g >> 18;
    int bn = b * N + row;
    float m = -1e30f;
    for (int s = 0; s < S; s++) m = fmaxf(m, part_m[s * (B * N) + bn]);
    float l = 0.f, y = 0.f;
    for (int s = 0; s < S; s++) {
        float w = __expf(part_m[s * (B * N) + bn] - m);
        l += part_l[s * (B * N) + bn] * w;
        y += part_y[((size_t)s * B * N + bn) * C + c] * w;
    }
    out[g] = y / l;
}

extern "C" void kernel_launch(void* const* d_in, const int* in_sizes, int n_in,
                              void* d_out, int out_size, void* d_ws, size_t ws_size,
                              hipStream_t stream) {
    const float* x      = (const float*)d_in[0];
    const float* dist   = (const float*)d_in[1];
    const float* proj_w = (const float*)d_in[2];
    const float* proj_b = (const float*)d_in[3];
    const float* a_w    = (const float*)d_in[4];
    float* out = (float*)d_out;

    char* ws = (char*)d_ws;
    short* h_bf   = (short*)(ws);                         // 2 MB
    short* hT_bf  = (short*)(ws + (2u << 20));            // 2 MB
    short* a_srcb = (short*)(ws + (4u << 20));            // 512 KB
    float* e2     = (float*)(ws + (4u << 20) + (512u << 10));  // 64 KB
    float* part_m = (float*)(ws + (5u << 20));            // up to 512 KB (S=8)
    float* part_l = (float*)(ws + (5u << 20) + (512u << 10));
    float* part_y = (float*)(ws + (6u << 20));            // S*4MB

    proj_kernel<<<N, 256, 0, stream>>>(x, proj_w, proj_b, a_w, h_bf, hT_bf, a_srcb, e2);

    int S = 8;
    while (S > 1 && (6u << 20) + (size_t)S * B * N * C * 4 > ws_size) S >>= 1;
    bool direct = ((6u << 20) + (size_t)B * N * C * 4 > ws_size);  // ultra-small ws fallback

    if (direct) {
        attn_kernel<<<dim3(N / 16, 1), 256, 0, stream>>>(
            dist, h_bf, hT_bf, a_srcb, e2, out, part_m, part_l, N, 1);
    } else {
        attn_kernel<<<dim3(N / 16, S), 256, 0, stream>>>(
            dist, h_bf, hT_bf, a_srcb, e2, part_y, part_m, part_l, N / S, 0);
        combine_kernel<<<(B * N * C) / 256, 256, 0, stream>>>(part_y, part_m, part_l, out, S);
    }
}